// Round 14
// baseline (158.387 us; speedup 1.0000x reference)
//
#include <hip/hip_runtime.h>

#define IN_SIZE 256
#define OUT_SIZE 64
#define N_NODES 512
#define FAN_IN 32
#define T_DIM 2048
#define D_DIM 832
#define TOTAL_EDGE 16384
#define BLK_F4 1088   // per-node: 1024 f4 butterfly pairs + 64 f4 entries
#define MAX_ENT 64
#define THRESH -20.0f

// DPP wave64 sum (lane 63 ends with total) — validated rounds 3..9
template <int CTRL, int RM>
__device__ __forceinline__ float dppadd(float v) {
  int m = __builtin_amdgcn_update_dpp(0, __float_as_int(v), CTRL, RM, 0xf, true);
  return v + __int_as_float(m);
}
__device__ __forceinline__ void wave_sum2(float& a, float& b) {
  a = dppadd<0x111, 0xf>(a); b = dppadd<0x111, 0xf>(b);
  a = dppadd<0x112, 0xf>(a); b = dppadd<0x112, 0xf>(b);
  a = dppadd<0x114, 0xf>(a); b = dppadd<0x114, 0xf>(b);
  a = dppadd<0x118, 0xf>(a); b = dppadd<0x118, 0xf>(b);
  a = dppadd<0x142, 0xa>(a); b = dppadd<0x142, 0xa>(b);
  a = dppadd<0x143, 0xc>(a); b = dppadd<0x143, 0xc>(b);
}
__device__ __forceinline__ float rl63(float v) {
  return __int_as_float(__builtin_amdgcn_readlane(__float_as_int(v), 63));
}

// ---------------------------------------------------------------------------
// KV build — ROUND-10 VERBATIM.
// ---------------------------------------------------------------------------
__global__ __launch_bounds__(512) void kv_kernel(
    const float* __restrict__ actives, const int* __restrict__ in_idxs,
    const float* __restrict__ weights, float2* __restrict__ KVd) {
  __shared__ float rows[8][836];     // 26752 B
  __shared__ int s_idx[64 * 33];     // 8448 B (stride 33: banks spread)
  __shared__ float s_raw[64 * 100];  // 25600 B (stride 100: banks spread)
  int tid = threadIdx.x;
  int tb = (blockIdx.x >> 1) * 8;
  int t0 = (blockIdx.x & 1) * 4;
#pragma unroll
  for (int r = 0; r < 8; ++r) {
    int t = tb + r;
    for (int c = tid; c < 208; c += 512) {  // 208 float4 = 832 floats
      float4 v4 = make_float4(0.f, 0.f, 0.f, 0.f);
      if (t < T_DIM - 1)
        v4 = ((const float4*)(actives + (size_t)(t + 1) * D_DIM))[c];
      *(float4*)&rows[r][4 * c] = v4;
    }
  }
  int tl = tid & 7, ng = tid >> 3;  // ng in [0,64)
  for (int tile = t0; tile < t0 + 4; ++tile) {
    __syncthreads();
    int n0 = tile * 64;
    for (int i = tid; i < 2048; i += 512) {
      int nl = i >> 5, f = i & 31;
      s_idx[nl * 33 + f] = in_idxs[n0 * FAN_IN + i];
    }
    {
      const float4* wsrc = (const float4*)(weights + (size_t)n0 * FAN_IN * 3);
      for (int i = tid; i < 1536; i += 512) {
        int nl = i / 24, j = i - nl * 24;
        *(float4*)&s_raw[nl * 100 + 4 * j] = wsrc[i];
      }
    }
    __syncthreads();
    {
      const int* ip = &s_idx[ng * 33];
      const float* wp = &s_raw[ng * 100];
      float k = 0.f, v = 0.f;
#pragma unroll 8
      for (int f = 0; f < FAN_IN; ++f) {
        float a = rows[tl][ip[f]];
        k = fmaf(wp[3 * f + 1], a, k);
        v = fmaf(wp[3 * f + 2], a, v);
      }
      KVd[(size_t)(n0 + ng) * (2 * BLK_F4) + tb + tl] = make_float2(k, v);
    }
  }
}

// ---------------------------------------------------------------------------
// Block build — ROUND-10 VERBATIM (512 threads, kv[4] regs, hist8).
// ---------------------------------------------------------------------------
__global__ __launch_bounds__(512) void block_kernel(
    const float* __restrict__ x, const int* __restrict__ in_idxs,
    const float* __restrict__ weights, float4* __restrict__ blk,
    float4* __restrict__ meta_g, float4* __restrict__ Qb) {
  __shared__ float2 sbk[T_DIM];  // 16 KB
  __shared__ int hist8[8][64];   // 2 KB
  __shared__ float smx[8], smn[8];
  __shared__ float4 sEnt[MAX_ENT];
  __shared__ int ecnt;
  int node = blockIdx.x, tid = threadIdx.x;
  int w = tid >> 6;  // wave 0..7
  if (tid == 0) ecnt = 0;
  if (tid < 64) {
#pragma unroll
    for (int ww = 0; ww < 8; ++ww) hist8[ww][tid] = 0;
  }
  const float2* src = (const float2*)(blk + (size_t)node * BLK_F4);
  float2 kv[4];
  float mx = -3.4e38f, mn = 3.4e38f;
#pragma unroll
  for (int j = 0; j < 4; ++j) {
    int t = j * 512 + tid;
    kv[j] = (t < 2047) ? src[t] : make_float2(0.f, 0.f);
    if (t < 2047) { mx = fmaxf(mx, kv[j].x); mn = fminf(mn, kv[j].x); }
  }
#pragma unroll
  for (int off = 32; off > 0; off >>= 1) {
    mx = fmaxf(mx, __shfl_xor(mx, off));
    mn = fminf(mn, __shfl_xor(mn, off));
  }
  if ((tid & 63) == 0) { smx[w] = mx; smn[w] = mn; }
  __syncthreads();
  float kmax = smx[0], kmin = smn[0];
#pragma unroll
  for (int ww = 1; ww < 8; ++ww) {
    kmax = fmaxf(kmax, smx[ww]);
    kmin = fminf(kmin, smn[ww]);
  }
  float invbw = 64.0f / (kmax - kmin);
#pragma unroll
  for (int j = 0; j < 4; ++j) {
    int t = j * 512 + tid;
    if (t < 2047) {
      int b = (int)((kv[j].x - kmin) * invbw);
      b = b < 0 ? 0 : (b > 63 ? 63 : b);
      atomicAdd(&hist8[w][b], 1);
    }
  }
  // consumer entries: edges e with in_idxs[e]==256+node and consumer > node
  {
    int target = IN_SIZE + node;
    const int4* ip4 = (const int4*)in_idxs;
#pragma unroll 4
    for (int e4 = tid; e4 < TOTAL_EDGE / 4; e4 += 512) {
      int4 v = ip4[e4];
      int e0 = 4 * e4;
#pragma unroll
      for (int c4 = 0; c4 < 4; ++c4) {
        int idx = c4 == 0 ? v.x : (c4 == 1 ? v.y : (c4 == 2 ? v.z : v.w));
        if (idx == target) {
          int e = e0 + c4;
          int c = e >> 5;
          if (c > node) {
            int p = atomicAdd(&ecnt, 1);
            if (p < MAX_ENT) {
              const float* wp = weights + (size_t)e * 3;
              sEnt[p] = make_float4(__int_as_float(c), wp[0], wp[1], wp[2]);
            }
          }
        }
      }
    }
  }
  // base dot from x (node inputs >= IN_SIZE contribute via scatters)
  if (tid < 32) {
    int g = node * FAN_IN + tid;
    int idx = in_idxs[g];
    const float* wp = weights + (size_t)g * 3;
    float a = (idx < IN_SIZE) ? x[idx] : 0.f;
    float p0 = a * wp[0], p1 = a * wp[1], p2 = a * wp[2];
#pragma unroll
    for (int off = 16; off > 0; off >>= 1) {
      p0 += __shfl_xor(p0, off);
      p1 += __shfl_xor(p1, off);
      p2 += __shfl_xor(p2, off);
    }
    if (tid == 0) Qb[node] = make_float4(p0, p1, p2, 0.f);
  }
  __syncthreads();
  // combined prefix + per-wave bucket bases (wave 0)
  if (tid < 64) {
    int h[8];
    int tot = 0;
#pragma unroll
    for (int ww = 0; ww < 8; ++ww) { h[ww] = hist8[ww][tid]; tot += h[ww]; }
    int incl = tot;
#pragma unroll
    for (int d = 1; d < 64; d <<= 1) {
      int u = __shfl_up(incl, d);
      if (tid >= d) incl += u;
    }
    int run = incl - tot;
#pragma unroll
    for (int ww = 0; ww < 8; ++ww) { hist8[ww][tid] = run; run += h[ww]; }
  }
  if (tid == 0) sbk[2047] = make_float2(0.f, 0.f);
  __syncthreads();
#pragma unroll
  for (int j = 0; j < 4; ++j) {
    int t = j * 512 + tid;
    if (t < 2047) {
      int b = (int)((kv[j].x - kmin) * invbw);
      b = b < 0 ? 0 : (b > 63 ? 63 : b);
      int p = atomicAdd(&hist8[w][b], 1);
      sbk[p] = kv[j];
    }
  }
  __syncthreads();
  float4* B = blk + (size_t)node * BLK_F4;
#pragma unroll
  for (int j = 0; j < 2; ++j) {
    int i = j * 512 + tid;
    float2 a = sbk[i];
    float2 d = sbk[2046 - i];
    B[i] = make_float4(a.x, a.y, d.x, d.y);
  }
  int cnt = ecnt < MAX_ENT ? ecnt : MAX_ENT;
  if (tid < MAX_ENT)
    B[1024 + tid] = (tid < cnt) ? sEnt[tid] : make_float4(0.f, 0.f, 0.f, 0.f);
  if (tid == 0)
    meta_g[3 * node + 0] =
        make_float4(kmax, kmin, __int_as_float(cnt), sbk[64].x);
  if (tid == 1)
    meta_g[3 * node + 1] =
        make_float4(sbk[1982].x, sbk[256].x, sbk[1790].x, sbk[512].x);
  if (tid == 2)
    meta_g[3 * node + 2] = make_float4(sbk[1534].x, 0.f, 0.f, 0.f);
}

// ---------------------------------------------------------------------------
// DATAFLOW sweep: banked structure + ONE delta this round: readiness counter
// FUSED into sQKV[n].x (values in .y/.z/.w). Consumer polls ONE float4 LDS
// read; when .x==need, q/k/v from the SAME read are final — the separate
// dependent sQKV read (~120 cy/link) disappears, as does sRecv (2 KB).
// Safety (uses r13-validated per-wave LDS in-order completion): producers
// do value-atomics (.y/.z/.w) THEN counter-atomic (.x). Single b128 poll:
// .x==need implies all counters landed, hence all earlier value-atomics.
// If the compiler splits the load, elements read in ascending address order
// sample .x FIRST — values read after counter observation: also safe.
// ---------------------------------------------------------------------------
__global__ __launch_bounds__(1024) void sweep_kernel(
    const int* __restrict__ in_idxs, const float4* __restrict__ Qb,
    const float4* __restrict__ meta_g, const float4* __restrict__ blk,
    float* __restrict__ out) {
  __shared__ float4 sQKV[N_NODES];  // (.x=recv count, .y=q, .z=k, .w=v)
  __shared__ float4 sMeta[N_NODES][3];
  __shared__ int sNeed[N_NODES];
  __shared__ float souts[OUT_SIZE];
  const int tid = threadIdx.x;
  const int lane = tid & 63;
  const int w = tid >> 6;

  for (int n = tid; n < N_NODES; n += 1024) {
    float4 qb = Qb[n];
    sQKV[n] = make_float4(0.f, qb.x, qb.y, qb.z);
    sMeta[n][0] = meta_g[3 * n + 0];
    sMeta[n][1] = meta_g[3 * n + 1];
    sMeta[n][2] = meta_g[3 * n + 2];
  }
  // live in-edge count per node (idx >= IN_SIZE and producer < node)
  if (tid < N_NODES) {
    const int4* ip = (const int4*)(in_idxs + tid * FAN_IN);
    int need = 0;
#pragma unroll
    for (int j = 0; j < 8; ++j) {
      int4 v = ip[j];
      need += (v.x >= IN_SIZE && v.x - IN_SIZE < tid);
      need += (v.y >= IN_SIZE && v.y - IN_SIZE < tid);
      need += (v.z >= IN_SIZE && v.z - IN_SIZE < tid);
      need += (v.w >= IN_SIZE && v.w - IN_SIZE < tid);
    }
    sNeed[tid] = need;
  }
  __syncthreads();

  auto process = [&](int node, float4 qv, float4 C0, float4 ENT, float4 m0,
                     float4 m1, float4 m2) {
    float q = qv.y, kl = qv.z, vl = qv.w;
    int cnt = __float_as_int(m0.z);
    float m = fmaxf(fmaxf(q * m0.x, q * m0.y), q * kl);
    bool p1 = fmaxf(q * m0.w, q * m1.x) - m >= THRESH;          // pairs 64..255
    bool p2 = p1 && (fmaxf(q * m1.y, q * m1.z) - m >= THRESH);  // 256..511
    bool p3 = p2 && (fmaxf(q * m1.w, q * m2.x) - m >= THRESH);  // 512..1023
    const float4* B = blk + (size_t)node * BLK_F4;
    float4 t1[3], t2[4], t3[8];
    if (p1) {
#pragma unroll
      for (int t = 0; t < 3; ++t) t1[t] = B[64 + 64 * t + lane];
    }
    if (p2) {
#pragma unroll
      for (int t = 0; t < 4; ++t) t2[t] = B[256 + 64 * t + lane];
    }
    if (p3) {
#pragma unroll
      for (int t = 0; t < 8; ++t) t3[t] = B[512 + 64 * t + lane];
    }
    float el = __expf(q * kl - m);
    float w0 = __expf(fmaf(q, C0.x, -m));
    float w1 = __expf(fmaf(q, C0.z, -m));
    float sw = w0 + w1;
    float swv = fmaf(w0, C0.y, w1 * C0.w);
    if (p1) {
#pragma unroll
      for (int t = 0; t < 3; ++t) {
        float a0 = __expf(fmaf(q, t1[t].x, -m));
        float a1 = __expf(fmaf(q, t1[t].z, -m));
        sw += a0 + a1;
        swv = fmaf(a0, t1[t].y, fmaf(a1, t1[t].w, swv));
      }
    }
    if (p2) {
#pragma unroll
      for (int t = 0; t < 4; ++t) {
        float a0 = __expf(fmaf(q, t2[t].x, -m));
        float a1 = __expf(fmaf(q, t2[t].z, -m));
        sw += a0 + a1;
        swv = fmaf(a0, t2[t].y, fmaf(a1, t2[t].w, swv));
      }
    }
    if (p3) {
#pragma unroll
      for (int t = 0; t < 8; ++t) {
        float a0 = __expf(fmaf(q, t3[t].x, -m));
        float a1 = __expf(fmaf(q, t3[t].z, -m));
        if (t == 7 && lane == 63) a1 = 0.f;  // pair 1023 desc = median dup
        sw += a0 + a1;
        swv = fmaf(a0, t3[t].y, fmaf(a1, t3[t].w, swv));
      }
    }
    wave_sum2(sw, swv);
    float S = rl63(sw) + el;
    float SV = fmaf(el, vl, rl63(swv));
    float z = SV * __builtin_amdgcn_rcpf(S);
    float eo = __expf(2.f * z);
    float o = 1.f - 2.f * __builtin_amdgcn_rcpf(eo + 1.f);
    if (lane == 0 && node >= N_NODES - OUT_SIZE)
      souts[node - (N_NODES - OUT_SIZE)] = o;
    // value-atomics then counter-atomic; per-wave LDS in-order (r13) means
    // a consumer observing .x==need observes all value contributions.
    if (lane < cnt) {
      int c = __float_as_int(ENT.x);
      atomicAdd(&sQKV[c].y, o * ENT.y);
      atomicAdd(&sQKV[c].z, o * ENT.z);
      atomicAdd(&sQKV[c].w, o * ENT.w);
      asm volatile("" ::: "memory");
      atomicAdd(&sQKV[c].x, 1.0f);
    }
  };

  auto pf = [&](int n, float4& c0, float4& ent, float4& m0, float4& m1,
                float4& m2) {
    const float4* B = blk + (size_t)n * BLK_F4;
    c0 = B[lane];
    ent = B[1024 + lane];
    m0 = sMeta[n][0];
    m1 = sMeta[n][1];
    m2 = sMeta[n][2];
  };

  // fused poll+read: one float4 LDS load per iteration; counter in .x.
  auto waitq = [&](int n) -> float4 {
    int need = sNeed[n];
    float4 qv;
    if (need > 0) {
      float fneed = (float)need;
      int it = 0;
      for (;;) {
        asm volatile("" ::: "memory");  // force re-load each iteration
        qv = *(const float4*)&sQKV[n];
        if (qv.x >= fneed || ++it >= 1000000) break;
        __builtin_amdgcn_s_sleep(1);
      }
    } else {
      asm volatile("" ::: "memory");
      qv = *(const float4*)&sQKV[n];
    }
    asm volatile("" ::: "memory");
    return qv;
  };

  float4 c0A, entA, m0A, m1A, m2A;
  float4 c0B, entB, m0B, m1B, m2B;
  pf(w, c0A, entA, m0A, m1A, m2A);
  for (int n = w; n < N_NODES; n += 32) {
    pf(n + 16, c0B, entB, m0B, m1B, m2B);
    float4 qvA = waitq(n);
    process(n, qvA, c0A, entA, m0A, m1A, m2A);
    if (n + 32 < N_NODES) pf(n + 32, c0A, entA, m0A, m1A, m2A);
    float4 qvB = waitq(n + 16);
    process(n + 16, qvB, c0B, entB, m0B, m1B, m2B);
  }
  __syncthreads();
  if (tid < OUT_SIZE) out[tid] = souts[tid];
}

// ---------------------------------------------------------------------------
extern "C" void kernel_launch(void* const* d_in, const int* in_sizes, int n_in,
                              void* d_out, int out_size, void* d_ws,
                              size_t ws_size, hipStream_t stream) {
  const float* x = (const float*)d_in[0];
  const float* actives = (const float*)d_in[1];
  const float* weights = (const float*)d_in[2];
  const int* in_idxs = (const int*)d_in[3];
  float* out = (float*)d_out;

  // workspace (~9.0 MB): blk | meta_g | Qb
  char* ws = (char*)d_ws;
  float4* blk = (float4*)ws;  // 512 * 1088 * 16 = 8,912,896 B
  size_t off = (size_t)N_NODES * BLK_F4 * 16;
  float4* meta_g = (float4*)(ws + off); off += (size_t)N_NODES * 3 * 16;
  float4* Qb = (float4*)(ws + off);

  kv_kernel<<<(T_DIM / 8) * 2, 512, 0, stream>>>(actives, in_idxs, weights,
                                                 (float2*)blk);
  block_kernel<<<N_NODES, 512, 0, stream>>>(x, in_idxs, weights, blk, meta_g,
                                            Qb);
  sweep_kernel<<<1, 1024, 0, stream>>>(in_idxs, Qb, meta_g, blk, out);
}

// Round 15
// 155.151 us; speedup vs baseline: 1.0209x; 1.0209x over previous
//
#include <hip/hip_runtime.h>

#define IN_SIZE 256
#define OUT_SIZE 64
#define N_NODES 512
#define FAN_IN 32
#define T_DIM 2048
#define D_DIM 832
#define TOTAL_EDGE 16384
#define BLK_F4 1088   // per-node: 1024 f4 butterfly pairs + 64 f4 entries
#define MAX_ENT 64
#define THRESH -20.0f

// DPP wave64 sum (lane 63 ends with total) — validated rounds 3..9
template <int CTRL, int RM>
__device__ __forceinline__ float dppadd(float v) {
  int m = __builtin_amdgcn_update_dpp(0, __float_as_int(v), CTRL, RM, 0xf, true);
  return v + __int_as_float(m);
}
__device__ __forceinline__ void wave_sum2(float& a, float& b) {
  a = dppadd<0x111, 0xf>(a); b = dppadd<0x111, 0xf>(b);
  a = dppadd<0x112, 0xf>(a); b = dppadd<0x112, 0xf>(b);
  a = dppadd<0x114, 0xf>(a); b = dppadd<0x114, 0xf>(b);
  a = dppadd<0x118, 0xf>(a); b = dppadd<0x118, 0xf>(b);
  a = dppadd<0x142, 0xa>(a); b = dppadd<0x142, 0xa>(b);
  a = dppadd<0x143, 0xc>(a); b = dppadd<0x143, 0xc>(b);
}
__device__ __forceinline__ float rl63(float v) {
  return __int_as_float(__builtin_amdgcn_readlane(__float_as_int(v), 63));
}

// ---------------------------------------------------------------------------
// KV build — ROUND-10 VERBATIM.
// ---------------------------------------------------------------------------
__global__ __launch_bounds__(512) void kv_kernel(
    const float* __restrict__ actives, const int* __restrict__ in_idxs,
    const float* __restrict__ weights, float2* __restrict__ KVd) {
  __shared__ float rows[8][836];     // 26752 B
  __shared__ int s_idx[64 * 33];     // 8448 B (stride 33: banks spread)
  __shared__ float s_raw[64 * 100];  // 25600 B (stride 100: banks spread)
  int tid = threadIdx.x;
  int tb = (blockIdx.x >> 1) * 8;
  int t0 = (blockIdx.x & 1) * 4;
#pragma unroll
  for (int r = 0; r < 8; ++r) {
    int t = tb + r;
    for (int c = tid; c < 208; c += 512) {  // 208 float4 = 832 floats
      float4 v4 = make_float4(0.f, 0.f, 0.f, 0.f);
      if (t < T_DIM - 1)
        v4 = ((const float4*)(actives + (size_t)(t + 1) * D_DIM))[c];
      *(float4*)&rows[r][4 * c] = v4;
    }
  }
  int tl = tid & 7, ng = tid >> 3;  // ng in [0,64)
  for (int tile = t0; tile < t0 + 4; ++tile) {
    __syncthreads();
    int n0 = tile * 64;
    for (int i = tid; i < 2048; i += 512) {
      int nl = i >> 5, f = i & 31;
      s_idx[nl * 33 + f] = in_idxs[n0 * FAN_IN + i];
    }
    {
      const float4* wsrc = (const float4*)(weights + (size_t)n0 * FAN_IN * 3);
      for (int i = tid; i < 1536; i += 512) {
        int nl = i / 24, j = i - nl * 24;
        *(float4*)&s_raw[nl * 100 + 4 * j] = wsrc[i];
      }
    }
    __syncthreads();
    {
      const int* ip = &s_idx[ng * 33];
      const float* wp = &s_raw[ng * 100];
      float k = 0.f, v = 0.f;
#pragma unroll 8
      for (int f = 0; f < FAN_IN; ++f) {
        float a = rows[tl][ip[f]];
        k = fmaf(wp[3 * f + 1], a, k);
        v = fmaf(wp[3 * f + 2], a, v);
      }
      KVd[(size_t)(n0 + ng) * (2 * BLK_F4) + tb + tl] = make_float2(k, v);
    }
  }
}

// ---------------------------------------------------------------------------
// Block build — ROUND-10 VERBATIM (512 threads, kv[4] regs, hist8).
// ---------------------------------------------------------------------------
__global__ __launch_bounds__(512) void block_kernel(
    const float* __restrict__ x, const int* __restrict__ in_idxs,
    const float* __restrict__ weights, float4* __restrict__ blk,
    float4* __restrict__ meta_g, float4* __restrict__ Qb) {
  __shared__ float2 sbk[T_DIM];  // 16 KB
  __shared__ int hist8[8][64];   // 2 KB
  __shared__ float smx[8], smn[8];
  __shared__ float4 sEnt[MAX_ENT];
  __shared__ int ecnt;
  int node = blockIdx.x, tid = threadIdx.x;
  int w = tid >> 6;  // wave 0..7
  if (tid == 0) ecnt = 0;
  if (tid < 64) {
#pragma unroll
    for (int ww = 0; ww < 8; ++ww) hist8[ww][tid] = 0;
  }
  const float2* src = (const float2*)(blk + (size_t)node * BLK_F4);
  float2 kv[4];
  float mx = -3.4e38f, mn = 3.4e38f;
#pragma unroll
  for (int j = 0; j < 4; ++j) {
    int t = j * 512 + tid;
    kv[j] = (t < 2047) ? src[t] : make_float2(0.f, 0.f);
    if (t < 2047) { mx = fmaxf(mx, kv[j].x); mn = fminf(mn, kv[j].x); }
  }
#pragma unroll
  for (int off = 32; off > 0; off >>= 1) {
    mx = fmaxf(mx, __shfl_xor(mx, off));
    mn = fminf(mn, __shfl_xor(mn, off));
  }
  if ((tid & 63) == 0) { smx[w] = mx; smn[w] = mn; }
  __syncthreads();
  float kmax = smx[0], kmin = smn[0];
#pragma unroll
  for (int ww = 1; ww < 8; ++ww) {
    kmax = fmaxf(kmax, smx[ww]);
    kmin = fminf(kmin, smn[ww]);
  }
  float invbw = 64.0f / (kmax - kmin);
#pragma unroll
  for (int j = 0; j < 4; ++j) {
    int t = j * 512 + tid;
    if (t < 2047) {
      int b = (int)((kv[j].x - kmin) * invbw);
      b = b < 0 ? 0 : (b > 63 ? 63 : b);
      atomicAdd(&hist8[w][b], 1);
    }
  }
  // consumer entries: edges e with in_idxs[e]==256+node and consumer > node
  {
    int target = IN_SIZE + node;
    const int4* ip4 = (const int4*)in_idxs;
#pragma unroll 4
    for (int e4 = tid; e4 < TOTAL_EDGE / 4; e4 += 512) {
      int4 v = ip4[e4];
      int e0 = 4 * e4;
#pragma unroll
      for (int c4 = 0; c4 < 4; ++c4) {
        int idx = c4 == 0 ? v.x : (c4 == 1 ? v.y : (c4 == 2 ? v.z : v.w));
        if (idx == target) {
          int e = e0 + c4;
          int c = e >> 5;
          if (c > node) {
            int p = atomicAdd(&ecnt, 1);
            if (p < MAX_ENT) {
              const float* wp = weights + (size_t)e * 3;
              sEnt[p] = make_float4(__int_as_float(c), wp[0], wp[1], wp[2]);
            }
          }
        }
      }
    }
  }
  // base dot from x (node inputs >= IN_SIZE contribute via scatters)
  if (tid < 32) {
    int g = node * FAN_IN + tid;
    int idx = in_idxs[g];
    const float* wp = weights + (size_t)g * 3;
    float a = (idx < IN_SIZE) ? x[idx] : 0.f;
    float p0 = a * wp[0], p1 = a * wp[1], p2 = a * wp[2];
#pragma unroll
    for (int off = 16; off > 0; off >>= 1) {
      p0 += __shfl_xor(p0, off);
      p1 += __shfl_xor(p1, off);
      p2 += __shfl_xor(p2, off);
    }
    if (tid == 0) Qb[node] = make_float4(p0, p1, p2, 0.f);
  }
  __syncthreads();
  // combined prefix + per-wave bucket bases (wave 0)
  if (tid < 64) {
    int h[8];
    int tot = 0;
#pragma unroll
    for (int ww = 0; ww < 8; ++ww) { h[ww] = hist8[ww][tid]; tot += h[ww]; }
    int incl = tot;
#pragma unroll
    for (int d = 1; d < 64; d <<= 1) {
      int u = __shfl_up(incl, d);
      if (tid >= d) incl += u;
    }
    int run = incl - tot;
#pragma unroll
    for (int ww = 0; ww < 8; ++ww) { hist8[ww][tid] = run; run += h[ww]; }
  }
  if (tid == 0) sbk[2047] = make_float2(0.f, 0.f);
  __syncthreads();
#pragma unroll
  for (int j = 0; j < 4; ++j) {
    int t = j * 512 + tid;
    if (t < 2047) {
      int b = (int)((kv[j].x - kmin) * invbw);
      b = b < 0 ? 0 : (b > 63 ? 63 : b);
      int p = atomicAdd(&hist8[w][b], 1);
      sbk[p] = kv[j];
    }
  }
  __syncthreads();
  float4* B = blk + (size_t)node * BLK_F4;
#pragma unroll
  for (int j = 0; j < 2; ++j) {
    int i = j * 512 + tid;
    float2 a = sbk[i];
    float2 d = sbk[2046 - i];
    B[i] = make_float4(a.x, a.y, d.x, d.y);
  }
  int cnt = ecnt < MAX_ENT ? ecnt : MAX_ENT;
  if (tid < MAX_ENT)
    B[1024 + tid] = (tid < cnt) ? sEnt[tid] : make_float4(0.f, 0.f, 0.f, 0.f);
  if (tid == 0)
    meta_g[3 * node + 0] =
        make_float4(kmax, kmin, __int_as_float(cnt), sbk[64].x);
  if (tid == 1)
    meta_g[3 * node + 1] =
        make_float4(sbk[1982].x, sbk[256].x, sbk[1790].x, sbk[512].x);
  if (tid == 2)
    meta_g[3 * node + 2] = make_float4(sbk[1534].x, 0.f, 0.f, 0.f);
}

// ---------------------------------------------------------------------------
// DATAFLOW sweep: round-13 banked structure (separate sRecv, no-drain
// in-order signaling — r13-validated, absmax 0) + ONE delta: POLL
// DISCIPLINE. s_sleep(1) removed from the spin (poll period 190->~130 cy,
// avg detect -30..60 cy/link) and process() runs at s_setprio(1) so the
// chain-critical wave wins issue arbitration over the 15 polling waves.
// (r4 bundled these with the spilling t1-prefetch; r5 isolated the spill
// as the whole regression — this is their first clean test.)
// ---------------------------------------------------------------------------
__global__ __launch_bounds__(1024) void sweep_kernel(
    const int* __restrict__ in_idxs, const float4* __restrict__ Qb,
    const float4* __restrict__ meta_g, const float4* __restrict__ blk,
    float* __restrict__ out) {
  __shared__ float4 sQKV[N_NODES];
  __shared__ float4 sMeta[N_NODES][3];
  __shared__ int sRecv[N_NODES];
  __shared__ int sNeed[N_NODES];
  __shared__ float souts[OUT_SIZE];
  const int tid = threadIdx.x;
  const int lane = tid & 63;
  const int w = tid >> 6;

  for (int n = tid; n < N_NODES; n += 1024) {
    sQKV[n] = Qb[n];
    sMeta[n][0] = meta_g[3 * n + 0];
    sMeta[n][1] = meta_g[3 * n + 1];
    sMeta[n][2] = meta_g[3 * n + 2];
    sRecv[n] = 0;
  }
  // live in-edge count per node (idx >= IN_SIZE and producer < node)
  if (tid < N_NODES) {
    const int4* ip = (const int4*)(in_idxs + tid * FAN_IN);
    int need = 0;
#pragma unroll
    for (int j = 0; j < 8; ++j) {
      int4 v = ip[j];
      need += (v.x >= IN_SIZE && v.x - IN_SIZE < tid);
      need += (v.y >= IN_SIZE && v.y - IN_SIZE < tid);
      need += (v.z >= IN_SIZE && v.z - IN_SIZE < tid);
      need += (v.w >= IN_SIZE && v.w - IN_SIZE < tid);
    }
    sNeed[tid] = need;
  }
  __syncthreads();

  auto process = [&](int node, float4 C0, float4 ENT, float4 m0, float4 m1,
                     float4 m2) {
    float4 qv = sQKV[node];
    float q = qv.x, kl = qv.y, vl = qv.z;
    int cnt = __float_as_int(m0.z);
    float m = fmaxf(fmaxf(q * m0.x, q * m0.y), q * kl);
    bool p1 = fmaxf(q * m0.w, q * m1.x) - m >= THRESH;          // pairs 64..255
    bool p2 = p1 && (fmaxf(q * m1.y, q * m1.z) - m >= THRESH);  // 256..511
    bool p3 = p2 && (fmaxf(q * m1.w, q * m2.x) - m >= THRESH);  // 512..1023
    const float4* B = blk + (size_t)node * BLK_F4;
    float4 t1[3], t2[4], t3[8];
    if (p1) {
#pragma unroll
      for (int t = 0; t < 3; ++t) t1[t] = B[64 + 64 * t + lane];
    }
    if (p2) {
#pragma unroll
      for (int t = 0; t < 4; ++t) t2[t] = B[256 + 64 * t + lane];
    }
    if (p3) {
#pragma unroll
      for (int t = 0; t < 8; ++t) t3[t] = B[512 + 64 * t + lane];
    }
    float el = __expf(q * kl - m);
    float w0 = __expf(fmaf(q, C0.x, -m));
    float w1 = __expf(fmaf(q, C0.z, -m));
    float sw = w0 + w1;
    float swv = fmaf(w0, C0.y, w1 * C0.w);
    if (p1) {
#pragma unroll
      for (int t = 0; t < 3; ++t) {
        float a0 = __expf(fmaf(q, t1[t].x, -m));
        float a1 = __expf(fmaf(q, t1[t].z, -m));
        sw += a0 + a1;
        swv = fmaf(a0, t1[t].y, fmaf(a1, t1[t].w, swv));
      }
    }
    if (p2) {
#pragma unroll
      for (int t = 0; t < 4; ++t) {
        float a0 = __expf(fmaf(q, t2[t].x, -m));
        float a1 = __expf(fmaf(q, t2[t].z, -m));
        sw += a0 + a1;
        swv = fmaf(a0, t2[t].y, fmaf(a1, t2[t].w, swv));
      }
    }
    if (p3) {
#pragma unroll
      for (int t = 0; t < 8; ++t) {
        float a0 = __expf(fmaf(q, t3[t].x, -m));
        float a1 = __expf(fmaf(q, t3[t].z, -m));
        if (t == 7 && lane == 63) a1 = 0.f;  // pair 1023 desc = median dup
        sw += a0 + a1;
        swv = fmaf(a0, t3[t].y, fmaf(a1, t3[t].w, swv));
      }
    }
    wave_sum2(sw, swv);
    float S = rl63(sw) + el;
    float SV = fmaf(el, vl, rl63(swv));
    float z = SV * __builtin_amdgcn_rcpf(S);
    float eo = __expf(2.f * z);
    float o = 1.f - 2.f * __builtin_amdgcn_rcpf(eo + 1.f);
    if (lane == 0 && node >= N_NODES - OUT_SIZE)
      souts[node - (N_NODES - OUT_SIZE)] = o;
    // scatter to consumers, then release-signal. NO lgkm drain: per-wave LDS
    // ops execute in order (validated r13, absmax 0).
    if (lane < cnt) {
      int c = __float_as_int(ENT.x);
      atomicAdd(&sQKV[c].x, o * ENT.y);
      atomicAdd(&sQKV[c].y, o * ENT.z);
      atomicAdd(&sQKV[c].z, o * ENT.w);
      asm volatile("" ::: "memory");
      atomicAdd(&sRecv[c], 1);
    }
  };

  auto pf = [&](int n, float4& c0, float4& ent, float4& m0, float4& m1,
                float4& m2) {
    const float4* B = blk + (size_t)n * BLK_F4;
    c0 = B[lane];
    ent = B[1024 + lane];
    m0 = sMeta[n][0];
    m1 = sMeta[n][1];
    m2 = sMeta[n][2];
  };

  // tight poll: no s_sleep — poll period = LDS round-trip (~130 cy).
  auto spinwait = [&](int n) {
    int need = sNeed[n];
    if (need > 0) {
      const volatile int* rp = (const volatile int*)&sRecv[n];
      int it = 0;
      while (*rp < need && ++it < 2000000) {}
    }
    asm volatile("" ::: "memory");  // no sQKV read hoisted above readiness
  };

  float4 c0A, entA, m0A, m1A, m2A;
  float4 c0B, entB, m0B, m1B, m2B;
  pf(w, c0A, entA, m0A, m1A, m2A);
  for (int n = w; n < N_NODES; n += 32) {
    pf(n + 16, c0B, entB, m0B, m1B, m2B);
    spinwait(n);
    __builtin_amdgcn_s_setprio(1);
    process(n, c0A, entA, m0A, m1A, m2A);
    __builtin_amdgcn_s_setprio(0);
    if (n + 32 < N_NODES) pf(n + 32, c0A, entA, m0A, m1A, m2A);
    spinwait(n + 16);
    __builtin_amdgcn_s_setprio(1);
    process(n + 16, c0B, entB, m0B, m1B, m2B);
    __builtin_amdgcn_s_setprio(0);
  }
  __syncthreads();
  if (tid < OUT_SIZE) out[tid] = souts[tid];
}

// ---------------------------------------------------------------------------
extern "C" void kernel_launch(void* const* d_in, const int* in_sizes, int n_in,
                              void* d_out, int out_size, void* d_ws,
                              size_t ws_size, hipStream_t stream) {
  const float* x = (const float*)d_in[0];
  const float* actives = (const float*)d_in[1];
  const float* weights = (const float*)d_in[2];
  const int* in_idxs = (const int*)d_in[3];
  float* out = (float*)d_out;

  // workspace (~9.0 MB): blk | meta_g | Qb
  char* ws = (char*)d_ws;
  float4* blk = (float4*)ws;  // 512 * 1088 * 16 = 8,912,896 B
  size_t off = (size_t)N_NODES * BLK_F4 * 16;
  float4* meta_g = (float4*)(ws + off); off += (size_t)N_NODES * 3 * 16;
  float4* Qb = (float4*)(ws + off);

  kv_kernel<<<(T_DIM / 8) * 2, 512, 0, stream>>>(actives, in_idxs, weights,
                                                 (float2*)blk);
  block_kernel<<<N_NODES, 512, 0, stream>>>(x, in_idxs, weights, blk, meta_g,
                                            Qb);
  sweep_kernel<<<1, 1024, 0, stream>>>(in_idxs, Qb, meta_g, blk, out);
}